// Round 1
// baseline (876.795 us; speedup 1.0000x reference)
//
#include <hip/hip_runtime.h>

typedef unsigned short u16;
typedef short bf16x8 __attribute__((ext_vector_type(8)));
typedef float f32x4 __attribute__((ext_vector_type(4)));
typedef unsigned short u16x4 __attribute__((ext_vector_type(4)));

// B=2, T=2048, D=2048, H=16, dk=128, BH=32, M=B*T=4096
#define QK_SCALE 0.08838834764831845f

__device__ __forceinline__ u16 f2bf(float f) {
  unsigned u = __float_as_uint(f);
  u += 0x7fffu + ((u >> 16) & 1u);
  return (u16)(u >> 16);
}
__device__ __forceinline__ float bf2f(u16 h) { return __uint_as_float(((unsigned)h) << 16); }

__device__ __forceinline__ void gld_lds16(const u16* g, u16* l) {
  __builtin_amdgcn_global_load_lds(
      (const __attribute__((address_space(1))) void*)g,
      (__attribute__((address_space(3))) void*)l, 16, 0, 0);
}

// ---------------- f32 -> bf16 convert ----------------
__global__ void cvt_bf16_kernel(const float* __restrict__ in, u16* __restrict__ out, int n4) {
  int i = blockIdx.x * 256 + threadIdx.x;
  if (i >= n4) return;
  const float4 v = reinterpret_cast<const float4*>(in)[i];
  u16x4 o;
  o[0] = f2bf(v.x); o[1] = f2bf(v.y); o[2] = f2bf(v.z); o[3] = f2bf(v.w);
  reinterpret_cast<u16x4*>(out)[i] = o;
}

// ---------------- GEMM: C[m,n] = sum_k A[m,k]*Bw[n,k]  (both row-major, K inner) ----------------
// 128x128 tile, BK=32, 4 waves (2x2), each wave 64x64 = 4x4 16x16 frags. m97 structure.
// MODE 0: scatter bf16 into Q/K/V (B,H,T,dk) layout (N=6144 = [3][16][128] cols)
// MODE 1: write f32 to f_out (row-major M x n_out)
template<int MODE>
__global__ __launch_bounds__(256) void gemm_bt_kernel(
    const u16* __restrict__ A, const u16* __restrict__ Bw, int Kdim, int n_out,
    u16* __restrict__ q_out, u16* __restrict__ k_out, u16* __restrict__ v_out,
    float* __restrict__ f_out)
{
  __shared__ __align__(16) u16 As[128 * 32];
  __shared__ __align__(16) u16 Bs[128 * 32];
  const int t = threadIdx.x;
  const int lane = t & 63;
  const int w = t >> 6;
  const int wr = w >> 1, wc = w & 1;
  const int m0 = blockIdx.x * 128, n0 = blockIdx.y * 128;

  f32x4 acc[4][4];
#pragma unroll
  for (int m = 0; m < 4; ++m)
#pragma unroll
    for (int n = 0; n < 4; ++n)
#pragma unroll
      for (int i = 0; i < 4; ++i) acc[m][n][i] = 0.0f;

  // staging: LDS linear [row][32 elems]; issue j covers rows [j*64 + w*16 + lane/4]
  const int ob0 = w * 1024 + lane * 16;   // byte offset of issue 0
  const int row0 = ob0 >> 6;
  const int cole0 = (ob0 & 63) >> 1;
  const u16* gA0 = A + (size_t)(m0 + row0) * Kdim + cole0;
  const u16* gA1 = gA0 + (size_t)64 * Kdim;
  const u16* gB0 = Bw + (size_t)(n0 + row0) * Kdim + cole0;
  const u16* gB1 = gB0 + (size_t)64 * Kdim;
  u16* lA = As + w * 512;   // wave-uniform LDS base (+ lane*16B implicit)
  u16* lB = Bs + w * 512;

  const int l15 = lane & 15;
  const int kb = (lane >> 4) * 8;

  for (int k0 = 0; k0 < Kdim; k0 += 32) {
    __syncthreads();
    gld_lds16(gA0, lA);
    gld_lds16(gA1, lA + 2048);
    gld_lds16(gB0, lB);
    gld_lds16(gB1, lB + 2048);
    gA0 += 32; gA1 += 32; gB0 += 32; gB1 += 32;
    __syncthreads();
    bf16x8 a[4], b[4];
#pragma unroll
    for (int m = 0; m < 4; ++m)
      a[m] = *reinterpret_cast<const bf16x8*>(As + (wr * 64 + m * 16 + l15) * 32 + kb);
#pragma unroll
    for (int n = 0; n < 4; ++n)
      b[n] = *reinterpret_cast<const bf16x8*>(Bs + (wc * 64 + n * 16 + l15) * 32 + kb);
#pragma unroll
    for (int m = 0; m < 4; ++m)
#pragma unroll
      for (int n = 0; n < 4; ++n)
        acc[m][n] = __builtin_amdgcn_mfma_f32_16x16x32_bf16(a[m], b[n], acc[m][n], 0, 0, 0);
  }

  // epilogue: C row = m0 + wr*64 + m*16 + (lane>>4)*4 + r ; col = n0 + wc*64 + n*16 + (lane&15)
  const int rb = wr * 64 + ((lane >> 4) << 2);
  const int cbs = wc * 64 + l15;
  if (MODE == 0) {
#pragma unroll
    for (int n = 0; n < 4; ++n) {
      const int e = n0 + cbs + n * 16;        // col in [0,6144): (which, h, d)
      const int which = e >> 11;
      const int h = (e >> 7) & 15;
      const int d = e & 127;
      u16* dst = (which == 0) ? q_out : (which == 1) ? k_out : v_out;
#pragma unroll
      for (int m = 0; m < 4; ++m)
#pragma unroll
        for (int r = 0; r < 4; ++r) {
          const int bt = m0 + rb + m * 16 + r;
          const int bb = bt >> 11, tt = bt & 2047;
          dst[((size_t)(bb * 16 + h) * 2048 + tt) * 128 + d] = f2bf(acc[m][n][r]);
        }
    }
  } else {
#pragma unroll
    for (int m = 0; m < 4; ++m)
#pragma unroll
      for (int r = 0; r < 4; ++r) {
        const int row = m0 + rb + m * 16 + r;
#pragma unroll
        for (int n = 0; n < 4; ++n)
          f_out[(size_t)row * n_out + n0 + cbs + n * 16] = acc[m][n][r];
      }
  }
}

// ---------------- rotary (bug-faithful: angle = h * freqs[j]), in-place on Q (scaled) and K ----------------
__global__ void rotary_kernel(u16* __restrict__ Qb, u16* __restrict__ Kb) {
  const int idx = blockIdx.x * 256 + threadIdx.x;   // 32*2048*16 threads
  const int j4 = idx & 15;
  const int row = idx >> 4;                          // bh*2048 + t
  const int h = (row >> 11) & 15;
  const size_t base = (size_t)row * 128 + j4 * 4;
  float c[4], s[4];
#pragma unroll
  for (int i = 0; i < 4; ++i) {
    const int j = j4 * 4 + i;
    // freqs[j] = (1e-4)^(j/31) for j<32 else 0 ; ln(1e-4)/31 = -0.2971077539
    const float fr = (j < 32) ? __expf(-0.2971077539f * (float)j) : 0.0f;
    const float th = (float)h * fr;
    c[i] = cosf(th); s[i] = sinf(th);
  }
  {
    u16x4 u1 = *reinterpret_cast<u16x4*>(Qb + base);
    u16x4 u2 = *reinterpret_cast<u16x4*>(Qb + base + 64);
    u16x4 y1, y2;
#pragma unroll
    for (int i = 0; i < 4; ++i) {
      const float a = bf2f(u1[i]), b = bf2f(u2[i]);
      y1[i] = f2bf((a * c[i] + b * s[i]) * QK_SCALE);      // fold 1/sqrt(dk) into Q
      y2[i] = f2bf((b * c[i] - a * s[i]) * QK_SCALE);
    }
    *reinterpret_cast<u16x4*>(Qb + base) = y1;
    *reinterpret_cast<u16x4*>(Qb + base + 64) = y2;
  }
  {
    u16x4 u1 = *reinterpret_cast<u16x4*>(Kb + base);
    u16x4 u2 = *reinterpret_cast<u16x4*>(Kb + base + 64);
    u16x4 y1, y2;
#pragma unroll
    for (int i = 0; i < 4; ++i) {
      const float a = bf2f(u1[i]), b = bf2f(u2[i]);
      y1[i] = f2bf(a * c[i] + b * s[i]);
      y2[i] = f2bf(b * c[i] - a * s[i]);
    }
    *reinterpret_cast<u16x4*>(Kb + base) = y1;
    *reinterpret_cast<u16x4*>(Kb + base + 64) = y2;
  }
}

// ---------------- V transpose: (bh, t, d) -> (bh, d, t) ----------------
__global__ void transpose_v_kernel(const u16* __restrict__ V, u16* __restrict__ Vt) {
  __shared__ u16 tile[64][65];
  const int d0 = blockIdx.x * 64;
  const int t0 = blockIdx.y * 64;
  const int bh = blockIdx.z;
  const u16* src = V + (size_t)bh * (2048 * 128);
  u16* dst = Vt + (size_t)bh * (128 * 2048);
  const int tid = threadIdx.x;
  const int c4 = (tid & 15) * 4;
  const int r0 = tid >> 4;
#pragma unroll
  for (int p = 0; p < 4; ++p) {
    const int row = r0 + p * 16;
    const u16x4 v = *reinterpret_cast<const u16x4*>(src + (size_t)(t0 + row) * 128 + d0 + c4);
    tile[row][c4] = v[0]; tile[row][c4 + 1] = v[1];
    tile[row][c4 + 2] = v[2]; tile[row][c4 + 3] = v[3];
  }
  __syncthreads();
#pragma unroll
  for (int p = 0; p < 4; ++p) {
    const int dr = r0 + p * 16;
    u16x4 ov;
    ov[0] = tile[c4][dr]; ov[1] = tile[c4 + 1][dr];
    ov[2] = tile[c4 + 2][dr]; ov[3] = tile[c4 + 3][dr];
    *reinterpret_cast<u16x4*>(dst + (size_t)(d0 + dr) * 2048 + t0 + c4) = ov;
  }
}

// ---------------- flash attention: Q,K (bh,t,d) bf16 (Q pre-scaled), Vt (bh,d,t) bf16 ----------------
// grid (32 q-tiles of 64, 32 bh), 256 thr = 4 independent waves, 16 q-rows each. No barriers.
__global__ __launch_bounds__(256) void attn_kernel(
    const u16* __restrict__ Q, const u16* __restrict__ K,
    const u16* __restrict__ Vt, u16* __restrict__ O)
{
  __shared__ __align__(16) u16 p_lds[4][1024];   // 16x64 bf16 per wave, XOR-swizzled
  const int t = threadIdx.x, lane = t & 63, w = t >> 6;
  const int bh = blockIdx.y;
  const int q0 = blockIdx.x * 64 + w * 16;
  const int l15 = lane & 15, lhi = lane >> 4;
  const size_t qkb = (size_t)bh * (2048 * 128);

  bf16x8 aq[4];
  {
    const u16* qp = Q + qkb + (size_t)(q0 + l15) * 128 + lhi * 8;
#pragma unroll
    for (int ks = 0; ks < 4; ++ks) aq[ks] = *reinterpret_cast<const bf16x8*>(qp + ks * 32);
  }
  f32x4 o[8];
#pragma unroll
  for (int dt = 0; dt < 8; ++dt)
#pragma unroll
    for (int i = 0; i < 4; ++i) o[dt][i] = 0.0f;
  float mrow[4] = {-1e30f, -1e30f, -1e30f, -1e30f};
  float lrow[4] = {0.f, 0.f, 0.f, 0.f};
  const int rbase = q0 + (lhi << 2);
  const int ktmax = (q0 + 15) >> 6;
  char* pw = (char*)(&p_lds[w][0]);
  const u16* kbase = K + qkb + (size_t)l15 * 128 + lhi * 8;
  const u16* vbase = Vt + (size_t)bh * (128 * 2048) + (size_t)l15 * 2048 + lhi * 8;

  for (int kt = 0; kt <= ktmax; ++kt) {
    const int k0 = kt * 64;
    f32x4 s4[4];
#pragma unroll
    for (int nt = 0; nt < 4; ++nt)
#pragma unroll
      for (int i = 0; i < 4; ++i) s4[nt][i] = 0.0f;
    const u16* kp = kbase + (size_t)k0 * 128;
#pragma unroll
    for (int nt = 0; nt < 4; ++nt)
#pragma unroll
      for (int ks = 0; ks < 4; ++ks) {
        const bf16x8 bk = *reinterpret_cast<const bf16x8*>(kp + nt * (16 * 128) + ks * 32);
        s4[nt] = __builtin_amdgcn_mfma_f32_16x16x32_bf16(aq[ks], bk, s4[nt], 0, 0, 0);
      }
    if (kt == ktmax) {   // only the last k-tile can cross the diagonal
#pragma unroll
      for (int nt = 0; nt < 4; ++nt) {
        const int col = k0 + nt * 16 + l15;
#pragma unroll
        for (int r = 0; r < 4; ++r)
          if (col > rbase + r) s4[nt][r] = -1e30f;
      }
    }
    float alpha[4];
#pragma unroll
    for (int r = 0; r < 4; ++r) {
      float mx = fmaxf(fmaxf(s4[0][r], s4[1][r]), fmaxf(s4[2][r], s4[3][r]));
      mx = fmaxf(mx, __shfl_xor(mx, 1));
      mx = fmaxf(mx, __shfl_xor(mx, 2));
      mx = fmaxf(mx, __shfl_xor(mx, 4));
      mx = fmaxf(mx, __shfl_xor(mx, 8));
      const float mn = fmaxf(mrow[r], mx);
      alpha[r] = __expf(mrow[r] - mn);
      mrow[r] = mn;
    }
    float ps[4] = {0.f, 0.f, 0.f, 0.f};
#pragma unroll
    for (int nt = 0; nt < 4; ++nt)
#pragma unroll
      for (int r = 0; r < 4; ++r) {
        const float p = __expf(s4[nt][r] - mrow[r]);
        ps[r] += p;
        const int prow = (lhi << 2) + r;
        const int cbyte = (nt * 16 + l15) * 2;
        *(u16*)(pw + prow * 128 + (cbyte ^ ((prow & 7) << 4))) = f2bf(p);
      }
#pragma unroll
    for (int r = 0; r < 4; ++r) {
      float rs = ps[r];
      rs += __shfl_xor(rs, 1);
      rs += __shfl_xor(rs, 2);
      rs += __shfl_xor(rs, 4);
      rs += __shfl_xor(rs, 8);
      lrow[r] = lrow[r] * alpha[r] + rs;
#pragma unroll
      for (int dt = 0; dt < 8; ++dt) o[dt][r] *= alpha[r];
    }
    const u16* vp = vbase + k0;
#pragma unroll
    for (int ks = 0; ks < 2; ++ks) {
      const bf16x8 ap = *reinterpret_cast<const bf16x8*>(
          pw + l15 * 128 + ((ks * 64 + (lhi << 4)) ^ ((lane & 7) << 4)));
#pragma unroll
      for (int dt = 0; dt < 8; ++dt) {
        const bf16x8 bv = *reinterpret_cast<const bf16x8*>(vp + dt * (16 * 2048) + ks * 32);
        o[dt] = __builtin_amdgcn_mfma_f32_16x16x32_bf16(ap, bv, o[dt], 0, 0, 0);
      }
    }
  }
  const int bb = bh >> 4, h = bh & 15;
#pragma unroll
  for (int r = 0; r < 4; ++r) {
    const float inv = 1.0f / lrow[r];
    const int row = rbase + r;
    u16* op = O + (size_t)(bb * 2048 + row) * 2048 + h * 128 + l15;
#pragma unroll
    for (int dt = 0; dt < 8; ++dt) op[dt * 16] = f2bf(o[dt][r] * inv);
  }
}

extern "C" void kernel_launch(void* const* d_in, const int* in_sizes, int n_in,
                              void* d_out, int out_size, void* d_ws, size_t ws_size,
                              hipStream_t stream) {
  const float* x = (const float*)d_in[0];      // (2,2048,2048) f32
  const float* wqkv = (const float*)d_in[1];   // (6144,2048) f32
  const float* wo = (const float*)d_in[2];     // (2048,2048) f32
  float* out = (float*)d_out;                  // (2,2048,2048) f32
  u16* ws = (u16*)d_ws;

  u16* xb = ws;                    // 8,388,608 elems
  u16* wqkvb = xb + 8388608;       // 12,582,912
  u16* wob = wqkvb + 12582912;     // 4,194,304
  u16* Qb = wob + 4194304;         // 8,388,608
  u16* Kb = Qb + 8388608;          // 8,388,608
  u16* Vb = Kb + 8388608;          // 8,388,608  (total ~100.7 MB)
  u16* Vtb = wqkvb;                // alias: wqkvb dead after QKV GEMM
  u16* attn = xb;                  // alias: xb dead after QKV GEMM

  cvt_bf16_kernel<<<8192, 256, 0, stream>>>(x, xb, 2097152);
  cvt_bf16_kernel<<<12288, 256, 0, stream>>>(wqkv, wqkvb, 3145728);
  cvt_bf16_kernel<<<4096, 256, 0, stream>>>(wo, wob, 1048576);

  // QKV: M=4096, N=6144, K=2048 -> scatter to Q/K/V (B,H,T,dk) bf16
  gemm_bt_kernel<0><<<dim3(32, 48), 256, 0, stream>>>(xb, wqkvb, 2048, 0, Qb, Kb, Vb, nullptr);

  rotary_kernel<<<4096, 256, 0, stream>>>(Qb, Kb);
  transpose_v_kernel<<<dim3(2, 32, 32), 256, 0, stream>>>(Vb, Vtb);

  attn_kernel<<<dim3(32, 32), 256, 0, stream>>>(Qb, Kb, Vtb, attn);

  // Out proj: M=4096, N=2048, K=2048 -> f32 d_out
  gemm_bt_kernel<1><<<dim3(32, 16), 256, 0, stream>>>(attn, wob, 2048, 2048, nullptr, nullptr, nullptr, out);
}

// Round 2
// 327.180 us; speedup vs baseline: 2.6799x; 2.6799x over previous
//
#include <hip/hip_runtime.h>

typedef unsigned short u16;
typedef short bf16x8 __attribute__((ext_vector_type(8)));
typedef float f32x4 __attribute__((ext_vector_type(4)));
typedef unsigned short u16x4 __attribute__((ext_vector_type(4)));

// B=2, T=2048, D=2048, H=16, dk=128, BH=32, M=B*T=4096
#define QK_SCALE 0.08838834764831845f

__device__ __forceinline__ u16 f2bf(float f) {
  unsigned u = __float_as_uint(f);
  u += 0x7fffu + ((u >> 16) & 1u);
  return (u16)(u >> 16);
}
__device__ __forceinline__ float bf2f(u16 h) { return __uint_as_float(((unsigned)h) << 16); }

__device__ __forceinline__ void gld_lds16(const u16* g, u16* l) {
  __builtin_amdgcn_global_load_lds(
      (const __attribute__((address_space(1))) void*)g,
      (__attribute__((address_space(3))) void*)l, 16, 0, 0);
}

// ---------------- f32 -> bf16 convert ----------------
__global__ void cvt_bf16_kernel(const float* __restrict__ in, u16* __restrict__ out, int n4) {
  int i = blockIdx.x * 256 + threadIdx.x;
  if (i >= n4) return;
  const float4 v = reinterpret_cast<const float4*>(in)[i];
  u16x4 o;
  o[0] = f2bf(v.x); o[1] = f2bf(v.y); o[2] = f2bf(v.z); o[3] = f2bf(v.w);
  reinterpret_cast<u16x4*>(out)[i] = o;
}

// ---------------- GEMM: C[m,n] = sum_k A[m,k]*Bw[n,k]  (both row-major, K inner) ----------------
// 128x128 tile, BK=32, 4 waves (2x2), each wave 64x64 = 4x4 16x16 frags. m97 structure.
// MODE 0: scatter bf16 into Q/K/V (B,H,T,dk) layout (N=6144 = [3][16][128] cols)
// MODE 1: write f32 to f_out (row-major M x n_out)
template<int MODE>
__global__ __launch_bounds__(256) void gemm_bt_kernel(
    const u16* __restrict__ A, const u16* __restrict__ Bw, int Kdim, int n_out,
    u16* __restrict__ q_out, u16* __restrict__ k_out, u16* __restrict__ v_out,
    float* __restrict__ f_out)
{
  __shared__ __align__(16) u16 As[128 * 32];
  __shared__ __align__(16) u16 Bs[128 * 32];
  const int t = threadIdx.x;
  const int lane = t & 63;
  const int w = t >> 6;
  const int wr = w >> 1, wc = w & 1;
  const int m0 = blockIdx.x * 128, n0 = blockIdx.y * 128;

  f32x4 acc[4][4];
#pragma unroll
  for (int m = 0; m < 4; ++m)
#pragma unroll
    for (int n = 0; n < 4; ++n)
#pragma unroll
      for (int i = 0; i < 4; ++i) acc[m][n][i] = 0.0f;

  const int ob0 = w * 1024 + lane * 16;   // byte offset of issue 0
  const int row0 = ob0 >> 6;
  const int cole0 = (ob0 & 63) >> 1;
  const u16* gA0 = A + (size_t)(m0 + row0) * Kdim + cole0;
  const u16* gA1 = gA0 + (size_t)64 * Kdim;
  const u16* gB0 = Bw + (size_t)(n0 + row0) * Kdim + cole0;
  const u16* gB1 = gB0 + (size_t)64 * Kdim;
  u16* lA = As + w * 512;
  u16* lB = Bs + w * 512;

  const int l15 = lane & 15;
  const int kb = (lane >> 4) * 8;

  for (int k0 = 0; k0 < Kdim; k0 += 32) {
    __syncthreads();
    gld_lds16(gA0, lA);
    gld_lds16(gA1, lA + 2048);
    gld_lds16(gB0, lB);
    gld_lds16(gB1, lB + 2048);
    gA0 += 32; gA1 += 32; gB0 += 32; gB1 += 32;
    __syncthreads();
    bf16x8 a[4], b[4];
#pragma unroll
    for (int m = 0; m < 4; ++m)
      a[m] = *reinterpret_cast<const bf16x8*>(As + (wr * 64 + m * 16 + l15) * 32 + kb);
#pragma unroll
    for (int n = 0; n < 4; ++n)
      b[n] = *reinterpret_cast<const bf16x8*>(Bs + (wc * 64 + n * 16 + l15) * 32 + kb);
#pragma unroll
    for (int m = 0; m < 4; ++m)
#pragma unroll
      for (int n = 0; n < 4; ++n)
        acc[m][n] = __builtin_amdgcn_mfma_f32_16x16x32_bf16(a[m], b[n], acc[m][n], 0, 0, 0);
  }

  const int rb = wr * 64 + ((lane >> 4) << 2);
  const int cbs = wc * 64 + l15;
  if (MODE == 0) {
#pragma unroll
    for (int n = 0; n < 4; ++n) {
      const int e = n0 + cbs + n * 16;        // col in [0,6144): (which, h, d)
      const int which = e >> 11;
      const int h = (e >> 7) & 15;
      const int d = e & 127;
      u16* dst = (which == 0) ? q_out : (which == 1) ? k_out : v_out;
#pragma unroll
      for (int m = 0; m < 4; ++m)
#pragma unroll
        for (int r = 0; r < 4; ++r) {
          const int bt = m0 + rb + m * 16 + r;
          const int bb = bt >> 11, tt = bt & 2047;
          dst[((size_t)(bb * 16 + h) * 2048 + tt) * 128 + d] = f2bf(acc[m][n][r]);
        }
    }
  } else {
#pragma unroll
    for (int m = 0; m < 4; ++m)
#pragma unroll
      for (int r = 0; r < 4; ++r) {
        const int row = m0 + rb + m * 16 + r;
#pragma unroll
        for (int n = 0; n < 4; ++n)
          f_out[(size_t)row * n_out + n0 + cbs + n * 16] = acc[m][n][r];
      }
  }
}

// ---------------- rotary (bug-faithful: angle = h * freqs[j]), in-place on Q (scaled) and K ----------------
__global__ void rotary_kernel(u16* __restrict__ Qb, u16* __restrict__ Kb) {
  const int idx = blockIdx.x * 256 + threadIdx.x;   // 32*2048*16 threads
  const int j4 = idx & 15;
  const int row = idx >> 4;                          // bh*2048 + t
  const int h = (row >> 11) & 15;
  const size_t base = (size_t)row * 128 + j4 * 4;
  float c[4], s[4];
#pragma unroll
  for (int i = 0; i < 4; ++i) {
    const int j = j4 * 4 + i;
    const float fr = (j < 32) ? __expf(-0.2971077539f * (float)j) : 0.0f;
    const float th = (float)h * fr;
    c[i] = cosf(th); s[i] = sinf(th);
  }
  {
    u16x4 u1 = *reinterpret_cast<u16x4*>(Qb + base);
    u16x4 u2 = *reinterpret_cast<u16x4*>(Qb + base + 64);
    u16x4 y1, y2;
#pragma unroll
    for (int i = 0; i < 4; ++i) {
      const float a = bf2f(u1[i]), b = bf2f(u2[i]);
      y1[i] = f2bf((a * c[i] + b * s[i]) * QK_SCALE);
      y2[i] = f2bf((b * c[i] - a * s[i]) * QK_SCALE);
    }
    *reinterpret_cast<u16x4*>(Qb + base) = y1;
    *reinterpret_cast<u16x4*>(Qb + base + 64) = y2;
  }
  {
    u16x4 u1 = *reinterpret_cast<u16x4*>(Kb + base);
    u16x4 u2 = *reinterpret_cast<u16x4*>(Kb + base + 64);
    u16x4 y1, y2;
#pragma unroll
    for (int i = 0; i < 4; ++i) {
      const float a = bf2f(u1[i]), b = bf2f(u2[i]);
      y1[i] = f2bf(a * c[i] + b * s[i]);
      y2[i] = f2bf(b * c[i] - a * s[i]);
    }
    *reinterpret_cast<u16x4*>(Kb + base) = y1;
    *reinterpret_cast<u16x4*>(Kb + base + 64) = y2;
  }
}

// ---------------- V transpose: (bh, t, d) -> (bh, d, t) ----------------
__global__ void transpose_v_kernel(const u16* __restrict__ V, u16* __restrict__ Vt) {
  __shared__ u16 tile[64][65];
  const int d0 = blockIdx.x * 64;
  const int t0 = blockIdx.y * 64;
  const int bh = blockIdx.z;
  const u16* src = V + (size_t)bh * (2048 * 128);
  u16* dst = Vt + (size_t)bh * (128 * 2048);
  const int tid = threadIdx.x;
  const int c4 = (tid & 15) * 4;
  const int r0 = tid >> 4;
#pragma unroll
  for (int p = 0; p < 4; ++p) {
    const int row = r0 + p * 16;
    const u16x4 v = *reinterpret_cast<const u16x4*>(src + (size_t)(t0 + row) * 128 + d0 + c4);
    tile[row][c4] = v[0]; tile[row][c4 + 1] = v[1];
    tile[row][c4 + 2] = v[2]; tile[row][c4 + 3] = v[3];
  }
  __syncthreads();
#pragma unroll
  for (int p = 0; p < 4; ++p) {
    const int dr = r0 + p * 16;
    u16x4 ov;
    ov[0] = tile[c4][dr]; ov[1] = tile[c4 + 1][dr];
    ov[2] = tile[c4 + 2][dr]; ov[3] = tile[c4 + 3][dr];
    *reinterpret_cast<u16x4*>(dst + (size_t)(d0 + dr) * 2048 + t0 + c4) = ov;
  }
}

// ---------------- flash attention, LDS-staged K/V, double-buffered, load-balanced ----------------
// grid (16, 32): block bx handles q-tiles {bx, 31-bx} (constant 33 k-tiles/block).
// 4 waves x 16 q-rows = 64-row q-tile; K/V tiles (64 keys) staged via global_load_lds
// with pre-swizzled source (XOR chunk swizzle) + swizzled ds_read_b128 -> conflict-free.
__global__ __launch_bounds__(256) void attn_kernel(
    const u16* __restrict__ Q, const u16* __restrict__ K,
    const u16* __restrict__ Vt, u16* __restrict__ O)
{
  __shared__ __align__(16) u16 k_lds[2][64 * 128];   // 16KB/buf: [key t][d], chunk-swizzled
  __shared__ __align__(16) u16 v_lds[2][128 * 64];   // 16KB/buf: [d][key t], chunk-swizzled
  __shared__ __align__(16) u16 p_lds[4][1024];       // per-wave 16x64 P, swizzled
  const int t = threadIdx.x, lane = t & 63, w = t >> 6;
  const int bh = blockIdx.y;
  const int bx = blockIdx.x;
  const int l15 = lane & 15, lhi = lane >> 4;
  const size_t qkb = (size_t)bh * (2048 * 128);
  const u16* Kg = K + qkb;
  const u16* Vg = Vt + (size_t)bh * (size_t)(128 * 2048);
  char* pw = (char*)(&p_lds[w][0]);
  const int bb = bh >> 4, h = bh & 15;
  const int kxor = (l15 & 7) << 4;

  auto stage = [&](int buf, int k0) {
#pragma unroll
    for (int ii = 0; ii < 4; ++ii) {
      const int i = w * 4 + ii;
      const int krow = i * 4 + lhi;                       // LDS row this lane fills
      gld_lds16(Kg + (size_t)(k0 + krow) * 128 + (size_t)((l15 ^ (krow & 7)) * 8),
                &k_lds[buf][i * 512]);
    }
#pragma unroll
    for (int ii = 0; ii < 4; ++ii) {
      const int i = w * 4 + ii;
      const int vrow = i * 8 + (lane >> 3);               // d-row this lane fills
      gld_lds16(Vg + (size_t)vrow * 2048 + k0 + (size_t)(((lane & 7) ^ (vrow & 7)) * 8),
                &v_lds[buf][i * 512]);
    }
  };

  for (int half = 0; half < 2; ++half) {
    const int qt = half ? (31 - bx) : bx;
    const int q0 = qt * 64 + w * 16;
    bf16x8 aq[4];
    {
      const u16* qp = Q + qkb + (size_t)(q0 + l15) * 128 + lhi * 8;
#pragma unroll
      for (int ks = 0; ks < 4; ++ks) aq[ks] = *reinterpret_cast<const bf16x8*>(qp + ks * 32);
    }
    f32x4 o[8];
#pragma unroll
    for (int dt = 0; dt < 8; ++dt)
#pragma unroll
      for (int i = 0; i < 4; ++i) o[dt][i] = 0.0f;
    float mrow[4] = {-1e30f, -1e30f, -1e30f, -1e30f};
    float lrow[4] = {0.f, 0.f, 0.f, 0.f};
    const int rbase = q0 + (lhi << 2);
    const int ktmax = qt;

    __syncthreads();               // previous half's compute fully done before buffer reuse
    stage(0, 0);                   // prologue
    int cur = 0;
    for (int kt = 0; kt <= ktmax; ++kt) {
      __syncthreads();             // drains vmcnt -> buf[cur] ready; prev compute done
      if (kt < ktmax) stage(cur ^ 1, (kt + 1) * 64);   // prefetch overlaps compute below

      // ---- QK^T from k_lds[cur] ----
      const char* kbb = (const char*)(&k_lds[cur][0]);
      f32x4 s4[4];
#pragma unroll
      for (int nt = 0; nt < 4; ++nt)
#pragma unroll
        for (int i = 0; i < 4; ++i) s4[nt][i] = 0.0f;
#pragma unroll
      for (int nt = 0; nt < 4; ++nt) {
        const int krow = nt * 16 + l15;
#pragma unroll
        for (int ks = 0; ks < 4; ++ks) {
          const bf16x8 bk = *reinterpret_cast<const bf16x8*>(
              kbb + krow * 256 + ((ks * 64 + lhi * 16) ^ kxor));
          s4[nt] = __builtin_amdgcn_mfma_f32_16x16x32_bf16(aq[ks], bk, s4[nt], 0, 0, 0);
        }
      }
      if (kt == ktmax) {           // diagonal tile
#pragma unroll
        for (int nt = 0; nt < 4; ++nt) {
          const int col = kt * 64 + nt * 16 + l15;
#pragma unroll
          for (int r = 0; r < 4; ++r)
            if (col > rbase + r) s4[nt][r] = -1e30f;
        }
      }
      // ---- online softmax ----
      float alpha[4];
#pragma unroll
      for (int r = 0; r < 4; ++r) {
        float mx = fmaxf(fmaxf(s4[0][r], s4[1][r]), fmaxf(s4[2][r], s4[3][r]));
        mx = fmaxf(mx, __shfl_xor(mx, 1));
        mx = fmaxf(mx, __shfl_xor(mx, 2));
        mx = fmaxf(mx, __shfl_xor(mx, 4));
        mx = fmaxf(mx, __shfl_xor(mx, 8));
        const float mn = fmaxf(mrow[r], mx);
        alpha[r] = __expf(mrow[r] - mn);
        mrow[r] = mn;
      }
      float ps[4] = {0.f, 0.f, 0.f, 0.f};
#pragma unroll
      for (int nt = 0; nt < 4; ++nt)
#pragma unroll
        for (int r = 0; r < 4; ++r) {
          const float p = __expf(s4[nt][r] - mrow[r]);
          ps[r] += p;
          const int prow = (lhi << 2) + r;
          const int cbyte = (nt * 16 + l15) * 2;
          *(u16*)(pw + prow * 128 + (cbyte ^ ((prow & 7) << 4))) = f2bf(p);
        }
#pragma unroll
      for (int r = 0; r < 4; ++r) {
        float rs = ps[r];
        rs += __shfl_xor(rs, 1);
        rs += __shfl_xor(rs, 2);
        rs += __shfl_xor(rs, 4);
        rs += __shfl_xor(rs, 8);
        lrow[r] = lrow[r] * alpha[r] + rs;
#pragma unroll
        for (int dt = 0; dt < 8; ++dt) o[dt][r] *= alpha[r];
      }
      // ---- PV from v_lds[cur] ----
      const char* vbb = (const char*)(&v_lds[cur][0]);
#pragma unroll
      for (int ks2 = 0; ks2 < 2; ++ks2) {
        const bf16x8 ap = *reinterpret_cast<const bf16x8*>(
            pw + l15 * 128 + ((ks2 * 64 + (lhi << 4)) ^ kxor));
#pragma unroll
        for (int dt = 0; dt < 8; ++dt) {
          const int vrow = dt * 16 + l15;
          const bf16x8 bv = *reinterpret_cast<const bf16x8*>(
              vbb + vrow * 128 + ((ks2 * 64 + lhi * 16) ^ kxor));
          o[dt] = __builtin_amdgcn_mfma_f32_16x16x32_bf16(ap, bv, o[dt], 0, 0, 0);
        }
      }
      cur ^= 1;
    }
    // ---- write O tile ----
#pragma unroll
    for (int r = 0; r < 4; ++r) {
      const float inv = 1.0f / lrow[r];
      const int row = rbase + r;
      u16* op = O + (size_t)(bb * 2048 + row) * 2048 + h * 128 + l15;
#pragma unroll
      for (int dt = 0; dt < 8; ++dt) op[dt * 16] = f2bf(o[dt][r] * inv);
    }
  }
}

extern "C" void kernel_launch(void* const* d_in, const int* in_sizes, int n_in,
                              void* d_out, int out_size, void* d_ws, size_t ws_size,
                              hipStream_t stream) {
  const float* x = (const float*)d_in[0];      // (2,2048,2048) f32
  const float* wqkv = (const float*)d_in[1];   // (6144,2048) f32
  const float* wo = (const float*)d_in[2];     // (2048,2048) f32
  float* out = (float*)d_out;                  // (2,2048,2048) f32
  u16* ws = (u16*)d_ws;

  u16* xb = ws;                    // 8,388,608 elems
  u16* wqkvb = xb + 8388608;       // 12,582,912
  u16* wob = wqkvb + 12582912;     // 4,194,304
  u16* Qb = wob + 4194304;         // 8,388,608
  u16* Kb = Qb + 8388608;          // 8,388,608
  u16* Vb = Kb + 8388608;          // 8,388,608  (total ~100.7 MB)
  u16* Vtb = wqkvb;                // alias: wqkvb dead after QKV GEMM
  u16* attn = xb;                  // alias: xb dead after QKV GEMM

  cvt_bf16_kernel<<<8192, 256, 0, stream>>>(x, xb, 2097152);
  cvt_bf16_kernel<<<12288, 256, 0, stream>>>(wqkv, wqkvb, 3145728);
  cvt_bf16_kernel<<<4096, 256, 0, stream>>>(wo, wob, 1048576);

  // QKV: M=4096, N=6144, K=2048 -> scatter to Q/K/V (B,H,T,dk) bf16
  gemm_bt_kernel<0><<<dim3(32, 48), 256, 0, stream>>>(xb, wqkvb, 2048, 0, Qb, Kb, Vb, nullptr);

  rotary_kernel<<<4096, 256, 0, stream>>>(Qb, Kb);
  transpose_v_kernel<<<dim3(2, 32, 32), 256, 0, stream>>>(Vb, Vtb);

  attn_kernel<<<dim3(16, 32), 256, 0, stream>>>(Qb, Kb, Vtb, attn);

  // Out proj: M=4096, N=2048, K=2048 -> f32 d_out
  gemm_bt_kernel<1><<<dim3(32, 16), 256, 0, stream>>>(attn, wob, 2048, 2048, nullptr, nullptr, nullptr, out);
}

// Round 3
// 323.313 us; speedup vs baseline: 2.7119x; 1.0120x over previous
//
#include <hip/hip_runtime.h>

typedef unsigned short u16;
typedef short bf16x8 __attribute__((ext_vector_type(8)));
typedef float f32x4 __attribute__((ext_vector_type(4)));
typedef unsigned short u16x4 __attribute__((ext_vector_type(4)));

// B=2, T=2048, D=2048, H=16, dk=128, BH=32, M=B*T=4096
#define QK_SCALE 0.08838834764831845f

__device__ __forceinline__ u16 f2bf(float f) {
  unsigned u = __float_as_uint(f);
  u += 0x7fffu + ((u >> 16) & 1u);
  return (u16)(u >> 16);
}
__device__ __forceinline__ float bf2f(u16 h) { return __uint_as_float(((unsigned)h) << 16); }

__device__ __forceinline__ void gld_lds16(const u16* g, u16* l) {
  __builtin_amdgcn_global_load_lds(
      (const __attribute__((address_space(1))) void*)g,
      (__attribute__((address_space(3))) void*)l, 16, 0, 0);
}

// ---------------- f32 -> bf16 convert ----------------
__global__ void cvt_bf16_kernel(const float* __restrict__ in, u16* __restrict__ out, int n4) {
  int i = blockIdx.x * 256 + threadIdx.x;
  if (i >= n4) return;
  const float4 v = reinterpret_cast<const float4*>(in)[i];
  u16x4 o;
  o[0] = f2bf(v.x); o[1] = f2bf(v.y); o[2] = f2bf(v.z); o[3] = f2bf(v.w);
  reinterpret_cast<u16x4*>(out)[i] = o;
}

// ================= 256x256 8-phase GEMM (T2+T3+T4+T5), C=A*Bw^T =================
// 512 thr = 8 waves (2 row x 4 col), BK=64, LDS 128KB double-buffered,
// chunk-XOR swizzle both sides, counted vmcnt(4), raw s_barrier, setprio MFMA.
// MODE 0: scatter bf16 into Q/K/V (B,H,T,dk); cols = [3][16][128]
template<int MODE>
__global__ __launch_bounds__(512, 2) void gemm8p_kernel(
    const u16* __restrict__ A, const u16* __restrict__ Bw, int Kdim, int n_out,
    u16* __restrict__ q_out, u16* __restrict__ k_out, u16* __restrict__ v_out,
    float* __restrict__ f_out)
{
  __shared__ __align__(16) u16 As[2][256 * 64];
  __shared__ __align__(16) u16 Bs[2][256 * 64];
  const int t = threadIdx.x, lane = t & 63, w = t >> 6;
  const int wr = w >> 2, wc = w & 3;
  const int l15 = lane & 15, lhi = lane >> 4;
  const int m0 = blockIdx.x * 256, n0 = blockIdx.y * 256;
  const int NT = Kdim >> 6;

  // staging geometry: each issue = 512 lanes x 16B = 64 rows; lane covers
  // (row = wbase8 + lane>>3, chunk = lane&7); LDS linear, global pre-swizzled.
  const int srow = w * 8 + (lane >> 3);          // row within 64-row issue block
  const int gchunk = (lane & 7) ^ (srow & 7);    // involution: source chunk
  const size_t gcol = (size_t)gchunk * 8;

  auto stageA2 = [&](int buf, int kt2, int half) {   // one A half-tile (2 issues)
    const size_t kb = (size_t)kt2 * 64 + gcol;
#pragma unroll
    for (int i = 0; i < 2; ++i) {
      const int ro = half * 128 + i * 64;
      gld_lds16(A + (size_t)(m0 + srow + ro) * Kdim + kb, &As[buf][(w * 8 + ro) * 64]);
    }
  };
  auto stageB4 = [&](int buf, int kt2) {             // full B tile (4 issues)
    const size_t kb = (size_t)kt2 * 64 + gcol;
#pragma unroll
    for (int ro = 0; ro < 256; ro += 64)
      gld_lds16(Bw + (size_t)(n0 + srow + ro) * Kdim + kb, &Bs[buf][(w * 8 + ro) * 64]);
  };

  // ds_read addressing (swizzled): frag(m,k): row = wr*128+m*16+l15, chunk=(k*4+lhi)^(l15&7)
  const int arow0 = (wr * 128 + l15) * 64;
  const int brow0 = (wc * 64 + l15) * 64;
  const int koff0 = ((0 + lhi) ^ (l15 & 7)) * 8;
  const int koff1 = ((4 + lhi) ^ (l15 & 7)) * 8;

  f32x4 acc[8][4];
#pragma unroll
  for (int m = 0; m < 8; ++m)
#pragma unroll
    for (int n = 0; n < 4; ++n)
#pragma unroll
      for (int i = 0; i < 4; ++i) acc[m][n][i] = 0.0f;

  // prologue: A(0),B(0),A(1) then drain first 8 (tile 0 complete)
  stageA2(0, 0, 0); stageA2(0, 0, 1);
  stageB4(0, 0);
  if (NT > 1) { stageA2(1, 1, 0); stageA2(1, 1, 1); }
  asm volatile("s_waitcnt vmcnt(4)" ::: "memory");
  __builtin_amdgcn_s_barrier();

  for (int kt = 0; kt < NT; ++kt) {
    const int cur = kt & 1;
    const u16* __restrict__ Ac = &As[cur][0];
    const u16* __restrict__ Bc = &Bs[cur][0];
    bf16x8 aK1[4], a2K1[4], b0[4], b1[4];
    // ---------- P1: read A[m0-3] k0+k1, B k0; stage B(t+1); MFMA m0-3 x k0 ----------
    {
      bf16x8 aK0[4];
#pragma unroll
      for (int m = 0; m < 4; ++m) {
        aK0[m] = *reinterpret_cast<const bf16x8*>(Ac + arow0 + m * 1024 + koff0);
        aK1[m] = *reinterpret_cast<const bf16x8*>(Ac + arow0 + m * 1024 + koff1);
      }
#pragma unroll
      for (int n = 0; n < 4; ++n)
        b0[n] = *reinterpret_cast<const bf16x8*>(Bc + brow0 + n * 1024 + koff0);
      if (kt + 1 < NT) stageB4(cur ^ 1, kt + 1);
      __builtin_amdgcn_s_barrier();
      asm volatile("s_waitcnt lgkmcnt(0)" ::: "memory");
      __builtin_amdgcn_s_setprio(1);
#pragma unroll
      for (int m = 0; m < 4; ++m)
#pragma unroll
        for (int n = 0; n < 4; ++n)
          acc[m][n] = __builtin_amdgcn_mfma_f32_16x16x32_bf16(aK0[m], b0[n], acc[m][n], 0, 0, 0);
      __builtin_amdgcn_s_setprio(0);
      __builtin_amdgcn_s_barrier();
    }
    // ---------- P2: read A[m4-7] k0+k1, B k1; MFMA m4-7 x k0 ----------
    {
      bf16x8 a2K0[4];
#pragma unroll
      for (int m = 0; m < 4; ++m) {
        a2K0[m] = *reinterpret_cast<const bf16x8*>(Ac + arow0 + (m + 4) * 1024 + koff0);
        a2K1[m] = *reinterpret_cast<const bf16x8*>(Ac + arow0 + (m + 4) * 1024 + koff1);
      }
#pragma unroll
      for (int n = 0; n < 4; ++n)
        b1[n] = *reinterpret_cast<const bf16x8*>(Bc + brow0 + n * 1024 + koff1);
      __builtin_amdgcn_s_barrier();
      asm volatile("s_waitcnt lgkmcnt(0)" ::: "memory");
      __builtin_amdgcn_s_setprio(1);
#pragma unroll
      for (int m = 0; m < 4; ++m)
#pragma unroll
        for (int n = 0; n < 4; ++n)
          acc[m + 4][n] = __builtin_amdgcn_mfma_f32_16x16x32_bf16(a2K0[m], b0[n], acc[m + 4][n], 0, 0, 0);
      __builtin_amdgcn_s_setprio(0);
      __builtin_amdgcn_s_barrier();
    }
    // ---------- P3: stage A(t+2) half0 (As[cur] dead after P2 reads); MFMA m0-3 x k1 ----------
    if (kt + 2 < NT) stageA2(cur, kt + 2, 0);
    __builtin_amdgcn_s_barrier();
    __builtin_amdgcn_s_setprio(1);
#pragma unroll
    for (int m = 0; m < 4; ++m)
#pragma unroll
      for (int n = 0; n < 4; ++n)
        acc[m][n] = __builtin_amdgcn_mfma_f32_16x16x32_bf16(aK1[m], b1[n], acc[m][n], 0, 0, 0);
    __builtin_amdgcn_s_setprio(0);
    __builtin_amdgcn_s_barrier();
    // ---------- P4: stage A(t+2) half1; MFMA m4-7 x k1; counted vmcnt ----------
    if (kt + 2 < NT) stageA2(cur, kt + 2, 1);
    __builtin_amdgcn_s_barrier();
    __builtin_amdgcn_s_setprio(1);
#pragma unroll
    for (int m = 0; m < 4; ++m)
#pragma unroll
      for (int n = 0; n < 4; ++n)
        acc[m + 4][n] = __builtin_amdgcn_mfma_f32_16x16x32_bf16(a2K1[m], b1[n], acc[m + 4][n], 0, 0, 0);
    __builtin_amdgcn_s_setprio(0);
    if (kt < NT - 2) { asm volatile("s_waitcnt vmcnt(4)" ::: "memory"); }
    else             { asm volatile("s_waitcnt vmcnt(0)" ::: "memory"); }
    __builtin_amdgcn_s_barrier();
  }

  // epilogue: row = m0 + wr*128 + m*16 + lhi*4 + r ; col = n0 + wc*64 + n*16 + l15
  const int rb = wr * 128 + lhi * 4;
  const int cb = wc * 64 + l15;
  if (MODE == 0) {
#pragma unroll
    for (int n = 0; n < 4; ++n) {
      const int e = n0 + cb + n * 16;
      const int which = e >> 11;
      const int h = (e >> 7) & 15;
      const int d = e & 127;
      u16* dst = (which == 0) ? q_out : (which == 1) ? k_out : v_out;
#pragma unroll
      for (int m = 0; m < 8; ++m)
#pragma unroll
        for (int r = 0; r < 4; ++r) {
          const int bt = m0 + rb + m * 16 + r;
          const int bb = bt >> 11, tt = bt & 2047;
          dst[((size_t)(bb * 16 + h) * 2048 + tt) * 128 + d] = f2bf(acc[m][n][r]);
        }
    }
  } else {
#pragma unroll
    for (int m = 0; m < 8; ++m)
#pragma unroll
      for (int r = 0; r < 4; ++r) {
        const int row = m0 + rb + m * 16 + r;
#pragma unroll
        for (int n = 0; n < 4; ++n)
          f_out[(size_t)row * n_out + n0 + cb + n * 16] = acc[m][n][r];
      }
  }
}

// ---------------- m97-structure 128x128 GEMM (kept for the out-projection) ----------------
__global__ __launch_bounds__(256) void gemm_bt_kernel(
    const u16* __restrict__ A, const u16* __restrict__ Bw, int Kdim, int n_out,
    float* __restrict__ f_out)
{
  __shared__ __align__(16) u16 Asl[128 * 32];
  __shared__ __align__(16) u16 Bsl[128 * 32];
  const int t = threadIdx.x;
  const int lane = t & 63;
  const int w = t >> 6;
  const int wr = w >> 1, wc = w & 1;
  const int m0 = blockIdx.x * 128, n0 = blockIdx.y * 128;

  f32x4 acc[4][4];
#pragma unroll
  for (int m = 0; m < 4; ++m)
#pragma unroll
    for (int n = 0; n < 4; ++n)
#pragma unroll
      for (int i = 0; i < 4; ++i) acc[m][n][i] = 0.0f;

  const int ob0 = w * 1024 + lane * 16;
  const int row0 = ob0 >> 6;
  const int cole0 = (ob0 & 63) >> 1;
  const u16* gA0 = A + (size_t)(m0 + row0) * Kdim + cole0;
  const u16* gA1 = gA0 + (size_t)64 * Kdim;
  const u16* gB0 = Bw + (size_t)(n0 + row0) * Kdim + cole0;
  const u16* gB1 = gB0 + (size_t)64 * Kdim;
  u16* lA = Asl + w * 512;
  u16* lB = Bsl + w * 512;

  const int l15 = lane & 15;
  const int kb = (lane >> 4) * 8;

  for (int k0 = 0; k0 < Kdim; k0 += 32) {
    __syncthreads();
    gld_lds16(gA0, lA);
    gld_lds16(gA1, lA + 2048);
    gld_lds16(gB0, lB);
    gld_lds16(gB1, lB + 2048);
    gA0 += 32; gA1 += 32; gB0 += 32; gB1 += 32;
    __syncthreads();
    bf16x8 a[4], b[4];
#pragma unroll
    for (int m = 0; m < 4; ++m)
      a[m] = *reinterpret_cast<const bf16x8*>(Asl + (wr * 64 + m * 16 + l15) * 32 + kb);
#pragma unroll
    for (int n = 0; n < 4; ++n)
      b[n] = *reinterpret_cast<const bf16x8*>(Bsl + (wc * 64 + n * 16 + l15) * 32 + kb);
#pragma unroll
    for (int m = 0; m < 4; ++m)
#pragma unroll
      for (int n = 0; n < 4; ++n)
        acc[m][n] = __builtin_amdgcn_mfma_f32_16x16x32_bf16(a[m], b[n], acc[m][n], 0, 0, 0);
  }

  const int rb = wr * 64 + ((lane >> 4) << 2);
  const int cbs = wc * 64 + l15;
#pragma unroll
  for (int m = 0; m < 4; ++m)
#pragma unroll
    for (int r = 0; r < 4; ++r) {
      const int row = m0 + rb + m * 16 + r;
#pragma unroll
      for (int n = 0; n < 4; ++n)
        f_out[(size_t)row * n_out + n0 + cbs + n * 16] = acc[m][n][r];
    }
}

// ---------------- rotary (bug-faithful: angle = h * freqs[j]), in-place on Q (scaled) and K ----------------
__global__ void rotary_kernel(u16* __restrict__ Qb, u16* __restrict__ Kb) {
  const int idx = blockIdx.x * 256 + threadIdx.x;   // 32*2048*16 threads
  const int j4 = idx & 15;
  const int row = idx >> 4;                          // bh*2048 + t
  const int h = (row >> 11) & 15;
  const size_t base = (size_t)row * 128 + j4 * 4;
  float c[4], s[4];
#pragma unroll
  for (int i = 0; i < 4; ++i) {
    const int j = j4 * 4 + i;
    const float fr = (j < 32) ? __expf(-0.2971077539f * (float)j) : 0.0f;
    const float th = (float)h * fr;
    c[i] = cosf(th); s[i] = sinf(th);
  }
  {
    u16x4 u1 = *reinterpret_cast<u16x4*>(Qb + base);
    u16x4 u2 = *reinterpret_cast<u16x4*>(Qb + base + 64);
    u16x4 y1, y2;
#pragma unroll
    for (int i = 0; i < 4; ++i) {
      const float a = bf2f(u1[i]), b = bf2f(u2[i]);
      y1[i] = f2bf((a * c[i] + b * s[i]) * QK_SCALE);
      y2[i] = f2bf((b * c[i] - a * s[i]) * QK_SCALE);
    }
    *reinterpret_cast<u16x4*>(Qb + base) = y1;
    *reinterpret_cast<u16x4*>(Qb + base + 64) = y2;
  }
  {
    u16x4 u1 = *reinterpret_cast<u16x4*>(Kb + base);
    u16x4 u2 = *reinterpret_cast<u16x4*>(Kb + base + 64);
    u16x4 y1, y2;
#pragma unroll
    for (int i = 0; i < 4; ++i) {
      const float a = bf2f(u1[i]), b = bf2f(u2[i]);
      y1[i] = f2bf(a * c[i] + b * s[i]);
      y2[i] = f2bf(b * c[i] - a * s[i]);
    }
    *reinterpret_cast<u16x4*>(Kb + base) = y1;
    *reinterpret_cast<u16x4*>(Kb + base + 64) = y2;
  }
}

// ---------------- V transpose: (bh, t, d) -> (bh, d, t) ----------------
__global__ void transpose_v_kernel(const u16* __restrict__ V, u16* __restrict__ Vt) {
  __shared__ u16 tile[64][65];
  const int d0 = blockIdx.x * 64;
  const int t0 = blockIdx.y * 64;
  const int bh = blockIdx.z;
  const u16* src = V + (size_t)bh * (2048 * 128);
  u16* dst = Vt + (size_t)bh * (128 * 2048);
  const int tid = threadIdx.x;
  const int c4 = (tid & 15) * 4;
  const int r0 = tid >> 4;
#pragma unroll
  for (int p = 0; p < 4; ++p) {
    const int row = r0 + p * 16;
    const u16x4 v = *reinterpret_cast<const u16x4*>(src + (size_t)(t0 + row) * 128 + d0 + c4);
    tile[row][c4] = v[0]; tile[row][c4 + 1] = v[1];
    tile[row][c4 + 2] = v[2]; tile[row][c4 + 3] = v[3];
  }
  __syncthreads();
#pragma unroll
  for (int p = 0; p < 4; ++p) {
    const int dr = r0 + p * 16;
    u16x4 ov;
    ov[0] = tile[c4][dr]; ov[1] = tile[c4 + 1][dr];
    ov[2] = tile[c4 + 2][dr]; ov[3] = tile[c4 + 3][dr];
    *reinterpret_cast<u16x4*>(dst + (size_t)(d0 + dr) * 2048 + t0 + c4) = ov;
  }
}

// ---------------- flash attention, LDS-staged K/V, double-buffered, load-balanced ----------------
__global__ __launch_bounds__(256) void attn_kernel(
    const u16* __restrict__ Q, const u16* __restrict__ K,
    const u16* __restrict__ Vt, u16* __restrict__ O)
{
  __shared__ __align__(16) u16 k_lds[2][64 * 128];
  __shared__ __align__(16) u16 v_lds[2][128 * 64];
  __shared__ __align__(16) u16 p_lds[4][1024];
  const int t = threadIdx.x, lane = t & 63, w = t >> 6;
  const int bh = blockIdx.y;
  const int bx = blockIdx.x;
  const int l15 = lane & 15, lhi = lane >> 4;
  const size_t qkb = (size_t)bh * (2048 * 128);
  const u16* Kg = K + qkb;
  const u16* Vg = Vt + (size_t)bh * (size_t)(128 * 2048);
  char* pw = (char*)(&p_lds[w][0]);
  const int bb = bh >> 4, h = bh & 15;
  const int kxor = (l15 & 7) << 4;

  auto stage = [&](int buf, int k0) {
#pragma unroll
    for (int ii = 0; ii < 4; ++ii) {
      const int i = w * 4 + ii;
      const int krow = i * 4 + lhi;
      gld_lds16(Kg + (size_t)(k0 + krow) * 128 + (size_t)((l15 ^ (krow & 7)) * 8),
                &k_lds[buf][i * 512]);
    }
#pragma unroll
    for (int ii = 0; ii < 4; ++ii) {
      const int i = w * 4 + ii;
      const int vrow = i * 8 + (lane >> 3);
      gld_lds16(Vg + (size_t)vrow * 2048 + k0 + (size_t)(((lane & 7) ^ (vrow & 7)) * 8),
                &v_lds[buf][i * 512]);
    }
  };

  for (int half = 0; half < 2; ++half) {
    const int qt = half ? (31 - bx) : bx;
    const int q0 = qt * 64 + w * 16;
    bf16x8 aq[4];
    {
      const u16* qp = Q + qkb + (size_t)(q0 + l15) * 128 + lhi * 8;
#pragma unroll
      for (int ks = 0; ks < 4; ++ks) aq[ks] = *reinterpret_cast<const bf16x8*>(qp + ks * 32);
    }
    f32x4 o[8];
#pragma unroll
    for (int dt = 0; dt < 8; ++dt)
#pragma unroll
      for (int i = 0; i < 4; ++i) o[dt][i] = 0.0f;
    float mrow[4] = {-1e30f, -1e30f, -1e30f, -1e30f};
    float lrow[4] = {0.f, 0.f, 0.f, 0.f};
    const int rbase = q0 + (lhi << 2);
    const int ktmax = qt;

    __syncthreads();
    stage(0, 0);
    int cur = 0;
    for (int kt = 0; kt <= ktmax; ++kt) {
      __syncthreads();
      if (kt < ktmax) stage(cur ^ 1, (kt + 1) * 64);

      const char* kbb = (const char*)(&k_lds[cur][0]);
      f32x4 s4[4];
#pragma unroll
      for (int nt = 0; nt < 4; ++nt)
#pragma unroll
        for (int i = 0; i < 4; ++i) s4[nt][i] = 0.0f;
#pragma unroll
      for (int nt = 0; nt < 4; ++nt) {
        const int krow = nt * 16 + l15;
#pragma unroll
        for (int ks = 0; ks < 4; ++ks) {
          const bf16x8 bk = *reinterpret_cast<const bf16x8*>(
              kbb + krow * 256 + ((ks * 64 + lhi * 16) ^ kxor));
          s4[nt] = __builtin_amdgcn_mfma_f32_16x16x32_bf16(aq[ks], bk, s4[nt], 0, 0, 0);
        }
      }
      if (kt == ktmax) {
#pragma unroll
        for (int nt = 0; nt < 4; ++nt) {
          const int col = kt * 64 + nt * 16 + l15;
#pragma unroll
          for (int r = 0; r < 4; ++r)
            if (col > rbase + r) s4[nt][r] = -1e30f;
        }
      }
      float alpha[4];
#pragma unroll
      for (int r = 0; r < 4; ++r) {
        float mx = fmaxf(fmaxf(s4[0][r], s4[1][r]), fmaxf(s4[2][r], s4[3][r]));
        mx = fmaxf(mx, __shfl_xor(mx, 1));
        mx = fmaxf(mx, __shfl_xor(mx, 2));
        mx = fmaxf(mx, __shfl_xor(mx, 4));
        mx = fmaxf(mx, __shfl_xor(mx, 8));
        const float mn = fmaxf(mrow[r], mx);
        alpha[r] = __expf(mrow[r] - mn);
        mrow[r] = mn;
      }
      float ps[4] = {0.f, 0.f, 0.f, 0.f};
#pragma unroll
      for (int nt = 0; nt < 4; ++nt)
#pragma unroll
        for (int r = 0; r < 4; ++r) {
          const float p = __expf(s4[nt][r] - mrow[r]);
          ps[r] += p;
          const int prow = (lhi << 2) + r;
          const int cbyte = (nt * 16 + l15) * 2;
          *(u16*)(pw + prow * 128 + (cbyte ^ ((prow & 7) << 4))) = f2bf(p);
        }
#pragma unroll
      for (int r = 0; r < 4; ++r) {
        float rs = ps[r];
        rs += __shfl_xor(rs, 1);
        rs += __shfl_xor(rs, 2);
        rs += __shfl_xor(rs, 4);
        rs += __shfl_xor(rs, 8);
        lrow[r] = lrow[r] * alpha[r] + rs;
#pragma unroll
        for (int dt = 0; dt < 8; ++dt) o[dt][r] *= alpha[r];
      }
      const char* vbb = (const char*)(&v_lds[cur][0]);
#pragma unroll
      for (int ks2 = 0; ks2 < 2; ++ks2) {
        const bf16x8 ap = *reinterpret_cast<const bf16x8*>(
            pw + l15 * 128 + ((ks2 * 64 + (lhi << 4)) ^ kxor));
#pragma unroll
        for (int dt = 0; dt < 8; ++dt) {
          const int vrow = dt * 16 + l15;
          const bf16x8 bv = *reinterpret_cast<const bf16x8*>(
              vbb + vrow * 128 + ((ks2 * 64 + lhi * 16) ^ kxor));
          o[dt] = __builtin_amdgcn_mfma_f32_16x16x32_bf16(ap, bv, o[dt], 0, 0, 0);
        }
      }
      cur ^= 1;
    }
#pragma unroll
    for (int r = 0; r < 4; ++r) {
      const float inv = 1.0f / lrow[r];
      const int row = rbase + r;
      u16* op = O + (size_t)(bb * 2048 + row) * 2048 + h * 128 + l15;
#pragma unroll
      for (int dt = 0; dt < 8; ++dt) op[dt * 16] = f2bf(o[dt][r] * inv);
    }
  }
}

extern "C" void kernel_launch(void* const* d_in, const int* in_sizes, int n_in,
                              void* d_out, int out_size, void* d_ws, size_t ws_size,
                              hipStream_t stream) {
  const float* x = (const float*)d_in[0];      // (2,2048,2048) f32
  const float* wqkv = (const float*)d_in[1];   // (6144,2048) f32
  const float* wo = (const float*)d_in[2];     // (2048,2048) f32
  float* out = (float*)d_out;                  // (2,2048,2048) f32
  u16* ws = (u16*)d_ws;

  u16* xb = ws;                    // 8,388,608 elems
  u16* wqkvb = xb + 8388608;       // 12,582,912
  u16* wob = wqkvb + 12582912;     // 4,194,304
  u16* Qb = wob + 4194304;         // 8,388,608
  u16* Kb = Qb + 8388608;          // 8,388,608
  u16* Vb = Kb + 8388608;          // 8,388,608  (total ~100.7 MB)
  u16* Vtb = wqkvb;                // alias: wqkvb dead after QKV GEMM
  u16* attn = xb;                  // alias: xb dead after QKV GEMM

  cvt_bf16_kernel<<<8192, 256, 0, stream>>>(x, xb, 2097152);
  cvt_bf16_kernel<<<12288, 256, 0, stream>>>(wqkv, wqkvb, 3145728);
  cvt_bf16_kernel<<<4096, 256, 0, stream>>>(wo, wob, 1048576);

  // QKV: M=4096, N=6144, K=2048 -> scatter to Q/K/V (B,H,T,dk) bf16 (8-phase 256^2)
  gemm8p_kernel<0><<<dim3(16, 24), 512, 0, stream>>>(xb, wqkvb, 2048, 0, Qb, Kb, Vb, nullptr);

  rotary_kernel<<<4096, 256, 0, stream>>>(Qb, Kb);
  transpose_v_kernel<<<dim3(2, 32, 32), 256, 0, stream>>>(Vb, Vtb);

  attn_kernel<<<dim3(16, 32), 256, 0, stream>>>(Qb, Kb, Vtb, attn);

  // Out proj: M=4096, N=2048, K=2048 -> f32 d_out (m97 structure, 512 blocks)
  gemm_bt_kernel<<<dim3(32, 16), 256, 0, stream>>>(attn, wob, 2048, 2048, out);
}